// Round 12
// baseline (333.796 us; speedup 1.0000x reference)
//
#include <hip/hip_runtime.h>
#include <hip/hip_bf16.h>
#include <float.h>

// Problem constants (B,H,W,D,K) = (16,32,32,256,8192)
#define NROWS 16384
#define DDIM  256
#define KCB   8192
#define ZQ_ELEMS 4194304

// ws layout (~2.2 MB + counter)
#define WS_ESQ_OFF   0                      // float[8192]
#define WS_ZSQ_OFF   32768                  // float[16384]
#define WS_CAND_OFF  98304                  // u32[16384*32] = 2 MB
#define WS_PART_OFF  (98304 + 2097152)      // float[4096]
#define WS_CTR_OFF   (WS_PART_OFF + 16384)  // unsigned[1]

#define QWINDOW 410   // rescore window: 0.025 in 1/16384 fixed-point quanta

typedef __attribute__((ext_vector_type(8))) short short8;
typedef __attribute__((ext_vector_type(4))) float floatx4;

__device__ __forceinline__ unsigned short bf16_rn(float f) {
    unsigned u = __float_as_uint(f);
    return (unsigned short)((u + 0x7FFFu + ((u >> 16) & 1u)) >> 16);
}

// async global->LDS DMA, 16 B per lane; LDS dest = wave-uniform base + lane*16
__device__ __forceinline__ void gload_lds16(const void* g, void* l) {
    __builtin_amdgcn_global_load_lds(
        (const __attribute__((address_space(1))) void*)(uintptr_t)g,
        (__attribute__((address_space(3))) void*)(unsigned)(uintptr_t)l, 16, 0, 0);
}

// ---------- prep: bf16 convert + numpy-pairwise sumsq (bit-exact, proven r3) ----
__global__ __launch_bounds__(256) void prep_kernel(
    const float* __restrict__ z, const float* __restrict__ cb,
    unsigned short* __restrict__ z16, unsigned short* __restrict__ cb16,
    float* __restrict__ esq, float* __restrict__ zsq, unsigned* __restrict__ ctr) {
#pragma clang fp contract(off)
    if (blockIdx.x == 0 && threadIdx.x == 0) *ctr = 0u;   // stream-ordered init
    int tid = threadIdx.x;
    int rowb = tid >> 2, sub = tid & 3;
    int b = sub >> 1, jq = sub & 1;
    int row = blockIdx.x * 64 + rowb;
    const float* src; unsigned short* dst; float* o;
    if (row < KCB) { src = cb + (size_t)row * DDIM; dst = cb16 + (size_t)row * DDIM; o = esq + row; }
    else { int r = row - KCB; src = z + (size_t)r * DDIM; dst = z16 + (size_t)r * DDIM; o = zsq + r; }
    float r0 = 0.f, r1 = 0.f, r2 = 0.f, r3 = 0.f;
#pragma unroll
    for (int t = 0; t < 16; ++t) {
        int off = b * 128 + t * 8 + jq * 4;
        float4 v = *(const float4*)(src + off);
        float q0 = v.x * v.x, q1 = v.y * v.y, q2 = v.z * v.z, q3 = v.w * v.w;
        r0 = r0 + q0; r1 = r1 + q1; r2 = r2 + q2; r3 = r3 + q3;
        ushort4 w;
        w.x = bf16_rn(v.x); w.y = bf16_rn(v.y); w.z = bf16_rn(v.z); w.w = bf16_rn(v.w);
        *(ushort4*)(dst + off) = w;
    }
    float s = (r0 + r1) + (r2 + r3);
    s = s + __shfl_xor(s, 1);   // jq pair
    s = s + __shfl_xor(s, 2);   // block pair
    if (sub == 0) *o = s;
}

// ---------- bf16 MFMA filter: R6 VERBATIM (best measured: 113.2us, absmax 0) ----
// block = 64 z-rows x 512 cols, 8 waves (wm,wn in 2x4), acc 64 regs/lane,
// 4 waves/SIMD. Schedule = proven per-step barrier loop.
__global__ __launch_bounds__(512, 4) void gemm_filter_kernel(
    const unsigned short* __restrict__ z16, const unsigned short* __restrict__ cb16,
    const float* __restrict__ esq, unsigned* __restrict__ cand) {
    __shared__ unsigned short As[64 * 256];     // 32 KB
    __shared__ unsigned short Bs[2][128 * 64];  // 2 x 16 KB
    __shared__ unsigned st[64][4][2];           // 2 KB cross-wave top-2 merge

    const int tid = threadIdx.x;
    const int w = tid >> 6, lane = tid & 63;
    const int wm = w >> 2, wn = w & 3;          // wave tile: rows wm*32+, cols wn*32 per chunk
    const int c = lane & 15, q = lane >> 4;
    const int m0 = blockIdx.y * 64;
    const int nbase = blockIdx.x * 512;

    // prologue: A tile (4 DMA ops/wave) + B chunk 0 (2 ops/wave)
#pragma unroll
    for (int p = 0; p < 4; ++p) {
        int s = (w * 4 + p) * 64 + lane;
        int row = s >> 5, jp = s & 31;
        int j = (jp & 24) | ((jp & 7) ^ (row & 7));   // source-addr XOR swizzle
        gload_lds16(z16 + (size_t)(m0 + row) * 256 + j * 8,
                    (char*)As + (w * 4 + p) * 1024);
    }
#pragma unroll
    for (int p = 0; p < 2; ++p) {
        int s = (w * 2 + p) * 64 + lane;
        int col = s >> 3, jp = s & 7;
        int j = jp ^ (col & 7);
        gload_lds16(cb16 + (size_t)(nbase + col) * 256 + j * 8,
                    (char*)Bs[0] + (w * 2 + p) * 1024);
    }
    __syncthreads();

    floatx4 acc[4][2][2];   // [ct][f][nf] — 64 regs
#pragma unroll
    for (int ct = 0; ct < 4; ++ct)
#pragma unroll
        for (int f = 0; f < 2; ++f)
#pragma unroll
            for (int nf = 0; nf < 2; ++nf) acc[ct][f][nf] = (floatx4){0.f, 0.f, 0.f, 0.f};

    short8 af[2][2];   // [f][ks] for current kt

#pragma unroll
    for (int s5 = 0; s5 < 16; ++s5) {
        const int kt = s5 >> 2, ct = s5 & 3, cur = s5 & 1;
        if (s5 < 15) {   // prefetch next cb chunk into other buffer
            const int nkt = (s5 + 1) >> 2, nct = (s5 + 1) & 3;
#pragma unroll
            for (int p = 0; p < 2; ++p) {
                int s = (w * 2 + p) * 64 + lane;
                int col = s >> 3, jp = s & 7;
                int j = jp ^ (col & 7);
                gload_lds16(cb16 + (size_t)(nbase + nct * 128 + col) * 256 + nkt * 64 + j * 8,
                            (char*)Bs[cur ^ 1] + (w * 2 + p) * 1024);
            }
        }
        if (ct == 0) {   // A-frags for this kt (reused across 4 ct)
#pragma unroll
            for (int f = 0; f < 2; ++f)
#pragma unroll
                for (int ks = 0; ks < 2; ++ks) {
                    int row = wm * 32 + f * 16 + c;
                    af[f][ks] = *(const short8*)((const char*)As + row * 512 +
                                 (kt * 8 + (((ks * 4 + q)) ^ (row & 7))) * 16);
                }
        }
        short8 bf[2][2];
#pragma unroll
        for (int nf = 0; nf < 2; ++nf)
#pragma unroll
            for (int ks = 0; ks < 2; ++ks) {
                int col = wn * 32 + nf * 16 + c;
                bf[nf][ks] = *(const short8*)((const char*)Bs[cur] + col * 128 +
                              (((ks * 4 + q) ^ (col & 7))) * 16);
            }
#pragma unroll
        for (int f = 0; f < 2; ++f)
#pragma unroll
            for (int nf = 0; nf < 2; ++nf) {
                acc[ct][f][nf] = __builtin_amdgcn_mfma_f32_16x16x32_bf16(
                    af[f][0], bf[nf][0], acc[ct][f][nf], 0, 0, 0);
                acc[ct][f][nf] = __builtin_amdgcn_mfma_f32_16x16x32_bf16(
                    af[f][1], bf[nf][1], acc[ct][f][nf], 0, 0, 0);
            }
        __syncthreads();   // buf cur consumed; next chunk's DMA drained here
    }

    // ---- epilogue (once per block): fixed-point pack + top-2 ----
    float ekf[4][2]; unsigned kb[4][2];
#pragma unroll
    for (int ct = 0; ct < 4; ++ct)
#pragma unroll
        for (int nf = 0; nf < 2; ++nf) {
            int col = nbase + ct * 128 + wn * 32 + nf * 16 + c;
            ekf[ct][nf] = (esq[col] + 8.0f) * 16384.0f;   // key+8 in quanta
            kb[ct][nf] = (unsigned)col;
        }
    unsigned b1[2][4], b2[2][4];
#pragma unroll
    for (int f = 0; f < 2; ++f)
#pragma unroll
        for (int r = 0; r < 4; ++r) { b1[f][r] = 0xFFFFFFFFu; b2[f][r] = 0xFFFFFFFFu; }
#pragma unroll
    for (int f = 0; f < 2; ++f)
#pragma unroll
        for (int r = 0; r < 4; ++r)
#pragma unroll
            for (int ct = 0; ct < 4; ++ct)
#pragma unroll
                for (int nf = 0; nf < 2; ++nf) {
                    float fx = fmaf(-32768.0f, acc[ct][f][nf][r], ekf[ct][nf]);
                    unsigned p = ((unsigned)fx << 13) | kb[ct][nf];
                    unsigned nb2;   // top-2 insert: b2 = med3(p,b1,b2); b1 = min(b1,p)
                    asm("v_med3_u32 %0, %1, %2, %3"
                        : "=v"(nb2) : "v"(p), "v"(b1[f][r]), "v"(b2[f][r]));
                    b2[f][r] = nb2;
                    b1[f][r] = min(b1[f][r], p);
                }
#pragma unroll
    for (int f = 0; f < 2; ++f)
#pragma unroll
        for (int r = 0; r < 4; ++r) {
            unsigned x1 = b1[f][r], x2 = b2[f][r];
#pragma unroll
            for (int sft = 1; sft < 16; sft <<= 1) {
                unsigned o1 = __shfl_xor(x1, sft);
                unsigned o2 = __shfl_xor(x2, sft);
                unsigned mx = max(x1, o1);
                x1 = min(x1, o1);
                x2 = min(min(mx, x2), o2);
            }
            if (c == 0) {
                st[wm * 32 + f * 16 + q * 4 + r][wn][0] = x1;
                st[wm * 32 + f * 16 + q * 4 + r][wn][1] = x2;
            }
        }
    __syncthreads();
    if (tid < 64) {
        unsigned a1 = st[tid][0][0], a2 = st[tid][0][1];
#pragma unroll
        for (int ww = 1; ww < 4; ++ww) {
            unsigned p1 = st[tid][ww][0], p2 = st[tid][ww][1];
            unsigned mx = max(a1, p1);
            a1 = min(a1, p1);
            a2 = min(min(mx, a2), p2);
        }
        cand[(size_t)(m0 + tid) * 32 + blockIdx.x * 2 + 0] = a1;
        cand[(size_t)(m0 + tid) * 32 + blockIdx.x * 2 + 1] = a2;
    }
}

// ---------- resolve (numpy-replica fp32 rescore) + gather + FUSED final --------
// Last-finishing block runs the byte-identical final reduction (same 256-thread
// indexing, same fp32 partial grouping, same double tree -> identical loss
// bits). Canonical last-block pattern: store -> __threadfence (device release)
// -> atomicAdd (device-scope, m20) -> last block __threadfence + atomic loads.
__global__ __launch_bounds__(256) void resolve_gather_kernel(
    const float* __restrict__ z, const float* __restrict__ cb,
    const float* __restrict__ zsq, const float* __restrict__ esq,
    const unsigned* __restrict__ cand, float* __restrict__ out,
    float* __restrict__ partials, unsigned* __restrict__ ctr) {
#pragma clang fp contract(off)
    __shared__ float wls[4];
    __shared__ unsigned isLast;
    int w = threadIdx.x >> 6, l = threadIdx.x & 63;
    int row = blockIdx.x * 4 + w;
    unsigned p = (l < 32) ? cand[(size_t)row * 32 + l] : 0xFFFFFFFFu;
    unsigned m = p;
#pragma unroll
    for (int s = 32; s; s >>= 1) m = min(m, __shfl_xor(m, s));
    bool active = (l < 32) && ((p >> 13) <= (m >> 13) + QWINDOW);
    float dref = FLT_MAX; int k = 0x7FFFFFFF;
    if (active) {
        k = (int)(p & 8191u);
        const float* zr = z + (size_t)row * DDIM;
        const float* er = cb + (size_t)k * DDIM;
        float cacc = 0.f;
        // float4 loads; fmaf chain sequence and order IDENTICAL to scalar loop
#pragma unroll 8
        for (int d = 0; d < DDIM; d += 4) {
            float4 zv = *(const float4*)(zr + d);
            float4 ev = *(const float4*)(er + d);
            cacc = fmaf(zv.x, ev.x, cacc);
            cacc = fmaf(zv.y, ev.y, cacc);
            cacc = fmaf(zv.z, ev.z, cacc);
            cacc = fmaf(zv.w, ev.w, cacc);
        }
        float s1 = zsq[row] + esq[k];          // numpy: z_sq + e_sq (fp32 round)
        float two = 2.0f * cacc;               // exact
        dref = s1 - two;                       // single fp32 round
    }
#pragma unroll
    for (int s = 32; s; s >>= 1) {
        float od = __shfl_xor(dref, s);
        int ok = __shfl_xor(k, s);
        if (od < dref || (od == dref && ok < k)) { dref = od; k = ok; }
    }
    if (l == 0) out[ZQ_ELEMS + row] = (float)k;
    float ls = 0.f;
#pragma unroll
    for (int t = 0; t < 4; ++t) {
        int d = l + t * 64;
        float e = cb[(size_t)k * DDIM + d];
        float zv = z[(size_t)row * DDIM + d];
        out[(size_t)row * DDIM + d] = zv + (e - zv);  // z_q_st == z_q numerically
        float df = zv - e;
        ls = fmaf(df, df, ls);
    }
#pragma unroll
    for (int s = 32; s; s >>= 1) ls += __shfl_xor(ls, s);
    if (l == 0) wls[w] = ls;
    __syncthreads();
    if (threadIdx.x == 0) {
        float pv = (wls[0] + wls[1]) + (wls[2] + wls[3]);   // exact same fp32 grouping
        partials[blockIdx.x] = pv;
        __threadfence();                      // device-scope release of the partial
        unsigned old = atomicAdd(ctr, 1u);    // device-scope by default [m20]
        isLast = (old == 4095u) ? 1u : 0u;
    }
    __syncthreads();
    if (isLast) {   // ---- final reduction: byte-identical to old final_kernel ----
        __shared__ double wd[4];
        if (threadIdx.x == 0) {
            __threadfence();                  // acquire side
            *ctr = 0u;                        // reset for graph replay (prep re-zeros too)
        }
        __syncthreads();
        double s = 0.0;
#pragma unroll
        for (int j = 0; j < 16; ++j) {
            unsigned u = __hip_atomic_load((const unsigned*)&partials[threadIdx.x + j * 256],
                                           __ATOMIC_RELAXED, __HIP_MEMORY_SCOPE_AGENT);
            s += (double)__uint_as_float(u);
        }
#pragma unroll
        for (int sh = 32; sh; sh >>= 1) s += __shfl_xor(s, sh);
        if (l == 0) wd[w] = s;
        __syncthreads();
        if (threadIdx.x == 0)
            out[ZQ_ELEMS + NROWS] =
                (float)(1.25 * ((wd[0] + wd[1]) + (wd[2] + wd[3])) / (double)ZQ_ELEMS);
    }
}

extern "C" void kernel_launch(void* const* d_in, const int* in_sizes, int n_in,
                              void* d_out, int out_size, void* d_ws, size_t ws_size,
                              hipStream_t stream) {
    const float* z = (const float*)d_in[0];
    const float* cb = (const float*)d_in[1];
    float* out = (float*)d_out;
    char* ws = (char*)d_ws;
    float* esq = (float*)(ws + WS_ESQ_OFF);
    float* zsq = (float*)(ws + WS_ZSQ_OFF);
    unsigned* cand = (unsigned*)(ws + WS_CAND_OFF);
    float* partials = (float*)(ws + WS_PART_OFF);
    unsigned* ctr = (unsigned*)(ws + WS_CTR_OFF);
    // bf16 scratch inside d_out (12 MB < 16.8 MB); overwritten by outputs later
    unsigned short* z16 = (unsigned short*)d_out;
    unsigned short* cb16 = z16 + (size_t)NROWS * DDIM;

    prep_kernel<<<dim3((KCB + NROWS) / 64), 256, 0, stream>>>(z, cb, z16, cb16, esq, zsq, ctr);
    gemm_filter_kernel<<<dim3(16, NROWS / 64), 512, 0, stream>>>(z16, cb16, esq, cand);
    resolve_gather_kernel<<<dim3(NROWS / 4), 256, 0, stream>>>(z, cb, zsq, esq, cand, out,
                                                               partials, ctr);
}

// Round 13
// 207.378 us; speedup vs baseline: 1.6096x; 1.6096x over previous
//
#include <hip/hip_runtime.h>
#include <hip/hip_bf16.h>
#include <float.h>

// Problem constants (B,H,W,D,K) = (16,32,32,256,8192)
#define NROWS 16384
#define DDIM  256
#define KCB   8192
#define ZQ_ELEMS 4194304

// ws layout (~2.2 MB; r0-proven)
#define WS_ESQ_OFF   0                      // float[8192]
#define WS_ZSQ_OFF   32768                  // float[16384]
#define WS_CAND_OFF  98304                  // u32[16384*32] = 2 MB
#define WS_PART_OFF  (98304 + 2097152)      // float[4096]

#define QWINDOW 410   // rescore window: 0.025 in 1/16384 fixed-point quanta

typedef __attribute__((ext_vector_type(8))) short short8;
typedef __attribute__((ext_vector_type(4))) float floatx4;

__device__ __forceinline__ unsigned short bf16_rn(float f) {
    unsigned u = __float_as_uint(f);
    return (unsigned short)((u + 0x7FFFu + ((u >> 16) & 1u)) >> 16);
}

// async global->LDS DMA, 16 B per lane; LDS dest = wave-uniform base + lane*16
__device__ __forceinline__ void gload_lds16(const void* g, void* l) {
    __builtin_amdgcn_global_load_lds(
        (const __attribute__((address_space(1))) void*)(uintptr_t)g,
        (__attribute__((address_space(3))) void*)(unsigned)(uintptr_t)l, 16, 0, 0);
}

// ---------- prep: bf16 convert + numpy-pairwise sumsq (bit-exact, proven r3) ----
__global__ __launch_bounds__(256) void prep_kernel(
    const float* __restrict__ z, const float* __restrict__ cb,
    unsigned short* __restrict__ z16, unsigned short* __restrict__ cb16,
    float* __restrict__ esq, float* __restrict__ zsq) {
#pragma clang fp contract(off)
    int tid = threadIdx.x;
    int rowb = tid >> 2, sub = tid & 3;
    int b = sub >> 1, jq = sub & 1;
    int row = blockIdx.x * 64 + rowb;
    const float* src; unsigned short* dst; float* o;
    if (row < KCB) { src = cb + (size_t)row * DDIM; dst = cb16 + (size_t)row * DDIM; o = esq + row; }
    else { int r = row - KCB; src = z + (size_t)r * DDIM; dst = z16 + (size_t)r * DDIM; o = zsq + r; }
    float r0 = 0.f, r1 = 0.f, r2 = 0.f, r3 = 0.f;
#pragma unroll
    for (int t = 0; t < 16; ++t) {
        int off = b * 128 + t * 8 + jq * 4;
        float4 v = *(const float4*)(src + off);
        float q0 = v.x * v.x, q1 = v.y * v.y, q2 = v.z * v.z, q3 = v.w * v.w;
        r0 = r0 + q0; r1 = r1 + q1; r2 = r2 + q2; r3 = r3 + q3;
        ushort4 w;
        w.x = bf16_rn(v.x); w.y = bf16_rn(v.y); w.z = bf16_rn(v.z); w.w = bf16_rn(v.w);
        *(ushort4*)(dst + off) = w;
    }
    float s = (r0 + r1) + (r2 + r3);
    s = s + __shfl_xor(s, 1);   // jq pair
    s = s + __shfl_xor(s, 2);   // block pair
    if (sub == 0) *o = s;
}

// ---------- bf16 MFMA filter: R6 VERBATIM (best measured: 113.2us, absmax 0) ----
__global__ __launch_bounds__(512, 4) void gemm_filter_kernel(
    const unsigned short* __restrict__ z16, const unsigned short* __restrict__ cb16,
    const float* __restrict__ esq, unsigned* __restrict__ cand) {
    __shared__ unsigned short As[64 * 256];     // 32 KB
    __shared__ unsigned short Bs[2][128 * 64];  // 2 x 16 KB
    __shared__ unsigned st[64][4][2];           // 2 KB cross-wave top-2 merge

    const int tid = threadIdx.x;
    const int w = tid >> 6, lane = tid & 63;
    const int wm = w >> 2, wn = w & 3;          // wave tile: rows wm*32+, cols wn*32 per chunk
    const int c = lane & 15, q = lane >> 4;
    const int m0 = blockIdx.y * 64;
    const int nbase = blockIdx.x * 512;

    // prologue: A tile (4 DMA ops/wave) + B chunk 0 (2 ops/wave)
#pragma unroll
    for (int p = 0; p < 4; ++p) {
        int s = (w * 4 + p) * 64 + lane;
        int row = s >> 5, jp = s & 31;
        int j = (jp & 24) | ((jp & 7) ^ (row & 7));   // source-addr XOR swizzle
        gload_lds16(z16 + (size_t)(m0 + row) * 256 + j * 8,
                    (char*)As + (w * 4 + p) * 1024);
    }
#pragma unroll
    for (int p = 0; p < 2; ++p) {
        int s = (w * 2 + p) * 64 + lane;
        int col = s >> 3, jp = s & 7;
        int j = jp ^ (col & 7);
        gload_lds16(cb16 + (size_t)(nbase + col) * 256 + j * 8,
                    (char*)Bs[0] + (w * 2 + p) * 1024);
    }
    __syncthreads();

    floatx4 acc[4][2][2];   // [ct][f][nf] — 64 regs
#pragma unroll
    for (int ct = 0; ct < 4; ++ct)
#pragma unroll
        for (int f = 0; f < 2; ++f)
#pragma unroll
            for (int nf = 0; nf < 2; ++nf) acc[ct][f][nf] = (floatx4){0.f, 0.f, 0.f, 0.f};

    short8 af[2][2];   // [f][ks] for current kt

#pragma unroll
    for (int s5 = 0; s5 < 16; ++s5) {
        const int kt = s5 >> 2, ct = s5 & 3, cur = s5 & 1;
        if (s5 < 15) {   // prefetch next cb chunk into other buffer
            const int nkt = (s5 + 1) >> 2, nct = (s5 + 1) & 3;
#pragma unroll
            for (int p = 0; p < 2; ++p) {
                int s = (w * 2 + p) * 64 + lane;
                int col = s >> 3, jp = s & 7;
                int j = jp ^ (col & 7);
                gload_lds16(cb16 + (size_t)(nbase + nct * 128 + col) * 256 + nkt * 64 + j * 8,
                            (char*)Bs[cur ^ 1] + (w * 2 + p) * 1024);
            }
        }
        if (ct == 0) {   // A-frags for this kt (reused across 4 ct)
#pragma unroll
            for (int f = 0; f < 2; ++f)
#pragma unroll
                for (int ks = 0; ks < 2; ++ks) {
                    int row = wm * 32 + f * 16 + c;
                    af[f][ks] = *(const short8*)((const char*)As + row * 512 +
                                 (kt * 8 + (((ks * 4 + q)) ^ (row & 7))) * 16);
                }
        }
        short8 bf[2][2];
#pragma unroll
        for (int nf = 0; nf < 2; ++nf)
#pragma unroll
            for (int ks = 0; ks < 2; ++ks) {
                int col = wn * 32 + nf * 16 + c;
                bf[nf][ks] = *(const short8*)((const char*)Bs[cur] + col * 128 +
                              (((ks * 4 + q) ^ (col & 7))) * 16);
            }
#pragma unroll
        for (int f = 0; f < 2; ++f)
#pragma unroll
            for (int nf = 0; nf < 2; ++nf) {
                acc[ct][f][nf] = __builtin_amdgcn_mfma_f32_16x16x32_bf16(
                    af[f][0], bf[nf][0], acc[ct][f][nf], 0, 0, 0);
                acc[ct][f][nf] = __builtin_amdgcn_mfma_f32_16x16x32_bf16(
                    af[f][1], bf[nf][1], acc[ct][f][nf], 0, 0, 0);
            }
        __syncthreads();   // buf cur consumed; next chunk's DMA drained here
    }

    // ---- epilogue (once per block): fixed-point pack + top-2 ----
    float ekf[4][2]; unsigned kb[4][2];
#pragma unroll
    for (int ct = 0; ct < 4; ++ct)
#pragma unroll
        for (int nf = 0; nf < 2; ++nf) {
            int col = nbase + ct * 128 + wn * 32 + nf * 16 + c;
            ekf[ct][nf] = (esq[col] + 8.0f) * 16384.0f;   // key+8 in quanta
            kb[ct][nf] = (unsigned)col;
        }
    unsigned b1[2][4], b2[2][4];
#pragma unroll
    for (int f = 0; f < 2; ++f)
#pragma unroll
        for (int r = 0; r < 4; ++r) { b1[f][r] = 0xFFFFFFFFu; b2[f][r] = 0xFFFFFFFFu; }
#pragma unroll
    for (int f = 0; f < 2; ++f)
#pragma unroll
        for (int r = 0; r < 4; ++r)
#pragma unroll
            for (int ct = 0; ct < 4; ++ct)
#pragma unroll
                for (int nf = 0; nf < 2; ++nf) {
                    float fx = fmaf(-32768.0f, acc[ct][f][nf][r], ekf[ct][nf]);
                    unsigned p = ((unsigned)fx << 13) | kb[ct][nf];
                    unsigned nb2;   // top-2 insert: b2 = med3(p,b1,b2); b1 = min(b1,p)
                    asm("v_med3_u32 %0, %1, %2, %3"
                        : "=v"(nb2) : "v"(p), "v"(b1[f][r]), "v"(b2[f][r]));
                    b2[f][r] = nb2;
                    b1[f][r] = min(b1[f][r], p);
                }
#pragma unroll
    for (int f = 0; f < 2; ++f)
#pragma unroll
        for (int r = 0; r < 4; ++r) {
            unsigned x1 = b1[f][r], x2 = b2[f][r];
#pragma unroll
            for (int sft = 1; sft < 16; sft <<= 1) {
                unsigned o1 = __shfl_xor(x1, sft);
                unsigned o2 = __shfl_xor(x2, sft);
                unsigned mx = max(x1, o1);
                x1 = min(x1, o1);
                x2 = min(min(mx, x2), o2);
            }
            if (c == 0) {
                st[wm * 32 + f * 16 + q * 4 + r][wn][0] = x1;
                st[wm * 32 + f * 16 + q * 4 + r][wn][1] = x2;
            }
        }
    __syncthreads();
    if (tid < 64) {
        unsigned a1 = st[tid][0][0], a2 = st[tid][0][1];
#pragma unroll
        for (int ww = 1; ww < 4; ++ww) {
            unsigned p1 = st[tid][ww][0], p2 = st[tid][ww][1];
            unsigned mx = max(a1, p1);
            a1 = min(a1, p1);
            a2 = min(min(mx, a2), p2);
        }
        cand[(size_t)(m0 + tid) * 32 + blockIdx.x * 2 + 0] = a1;
        cand[(size_t)(m0 + tid) * 32 + blockIdx.x * 2 + 1] = a2;
    }
}

// ---------- resolve: COALESCED-GATHER rescore + gather -------------------------
// R12 counters exposed resolve as the #2 cost (~95-160us): VALU 6.5%, HBM 2.7%,
// ~93% idle — request-rate bound on UNCOALESCED per-lane gathers of cb rows
// (each active lane streams its own 1KB row: every vmem instr splits into up to
// 32 transactions). FIX: per wave, stage active candidates' rows into LDS with
// fully-COALESCED cooperative loads (one 64-lane float4 instr per row), then
// run the bit-identical sequential fmaf chain from LDS (stride-257 pad: lane
// reads (slot*257+d), distinct slots -> distinct banks; z row broadcast).
// LDS copy preserves bits; chain order unchanged -> dref identical -> absmax 0.
// Up to 8 staged rows/wave (37KB/block); overflow lanes (rare) use the original
// global-memory chain (same fp order).
__global__ __launch_bounds__(256) void resolve_gather_kernel(
    const float* __restrict__ z, const float* __restrict__ cb,
    const float* __restrict__ zsq, const float* __restrict__ esq,
    const unsigned* __restrict__ cand, float* __restrict__ out,
    float* __restrict__ partials) {
#pragma clang fp contract(off)
    __shared__ float ers[4][8][257];   // 32.9 KB: staged candidate rows, padded
    __shared__ float zs[4][256];       // 4 KB: the wave's z row
    __shared__ float wls[4];
    int wv = threadIdx.x >> 6, l = threadIdx.x & 63;
    int row = blockIdx.x * 4 + wv;
    unsigned p = (l < 32) ? cand[(size_t)row * 32 + l] : 0xFFFFFFFFu;
    unsigned m = p;
#pragma unroll
    for (int s = 32; s; s >>= 1) m = min(m, __shfl_xor(m, s));
    bool active = (l < 32) && ((p >> 13) <= (m >> 13) + QWINDOW);
    int k = active ? (int)(p & 8191u) : 0x7FFFFFFF;

    // rank of this lane among active lanes; first 8 get LDS slots
    unsigned long long bal = __ballot(active);
    int slot = __popcll(bal & ((1ull << l) - 1ull));
    int nst = __popcll(bal); nst = nst < 8 ? nst : 8;

    // stage z row (coalesced, once per wave)
    {
        float4 v = *(const float4*)(z + (size_t)row * DDIM + l * 4);
        zs[wv][l * 4 + 0] = v.x; zs[wv][l * 4 + 1] = v.y;
        zs[wv][l * 4 + 2] = v.z; zs[wv][l * 4 + 3] = v.w;
    }
    // stage up to 8 candidate rows, one coalesced 1KB load each
    unsigned long long tmp = bal;
    for (int s = 0; s < nst; ++s) {
        int src = (int)__builtin_ctzll(tmp);
        tmp &= tmp - 1ull;
        int kk = __shfl(k, src, 64);
        float4 v = *(const float4*)(cb + (size_t)kk * DDIM + l * 4);
        ers[wv][s][l * 4 + 0] = v.x; ers[wv][s][l * 4 + 1] = v.y;
        ers[wv][s][l * 4 + 2] = v.z; ers[wv][s][l * 4 + 3] = v.w;
    }

    float dref = FLT_MAX;
    if (active) {
        float cacc = 0.f;
        if (slot < 8) {
            const float* zrow = &zs[wv][0];
            const float* erow = &ers[wv][slot][0];
#pragma unroll 8   // scheduling only: sequential fmaf chain order preserved
            for (int d = 0; d < DDIM; ++d)
                cacc = fmaf(zrow[d], erow[d], cacc);
        } else {     // overflow fallback: original global chain, same fp order
            const float* zr = z + (size_t)row * DDIM;
            const float* er = cb + (size_t)k * DDIM;
#pragma unroll 8
            for (int d = 0; d < DDIM; ++d)
                cacc = fmaf(zr[d], er[d], cacc);
        }
        float s1 = zsq[row] + esq[k];          // numpy: z_sq + e_sq (fp32 round)
        float two = 2.0f * cacc;               // exact
        dref = s1 - two;                       // single fp32 round
    }
#pragma unroll
    for (int s = 32; s; s >>= 1) {
        float od = __shfl_xor(dref, s);
        int ok = __shfl_xor(k, s);
        if (od < dref || (od == dref && ok < k)) { dref = od; k = ok; }
    }
    if (l == 0) out[ZQ_ELEMS + row] = (float)k;
    float ls = 0.f;
#pragma unroll
    for (int t = 0; t < 4; ++t) {
        int d = l + t * 64;
        float e = cb[(size_t)k * DDIM + d];     // winner row: same k wave-wide -> coalesced
        float zv = z[(size_t)row * DDIM + d];
        out[(size_t)row * DDIM + d] = zv + (e - zv);  // z_q_st == z_q numerically
        float df = zv - e;
        ls = fmaf(df, df, ls);
    }
#pragma unroll
    for (int s = 32; s; s >>= 1) ls += __shfl_xor(ls, s);
    if (l == 0) wls[wv] = ls;
    __syncthreads();
    if (threadIdx.x == 0)
        partials[blockIdx.x] = (wls[0] + wls[1]) + (wls[2] + wls[3]);
}

__global__ __launch_bounds__(256) void final_kernel(const float* __restrict__ partials,
                                                    float* __restrict__ out) {
    __shared__ double wd[4];
    int w = threadIdx.x >> 6, l = threadIdx.x & 63;
    double s = 0.0;
#pragma unroll
    for (int j = 0; j < 16; ++j) s += (double)partials[threadIdx.x + j * 256];
#pragma unroll
    for (int sh = 32; sh; sh >>= 1) s += __shfl_xor(s, sh);
    if (l == 0) wd[w] = s;
    __syncthreads();
    if (threadIdx.x == 0)
        out[ZQ_ELEMS + NROWS] =
            (float)(1.25 * ((wd[0] + wd[1]) + (wd[2] + wd[3])) / (double)ZQ_ELEMS);
}

extern "C" void kernel_launch(void* const* d_in, const int* in_sizes, int n_in,
                              void* d_out, int out_size, void* d_ws, size_t ws_size,
                              hipStream_t stream) {
    const float* z = (const float*)d_in[0];
    const float* cb = (const float*)d_in[1];
    float* out = (float*)d_out;
    char* ws = (char*)d_ws;
    float* esq = (float*)(ws + WS_ESQ_OFF);
    float* zsq = (float*)(ws + WS_ZSQ_OFF);
    unsigned* cand = (unsigned*)(ws + WS_CAND_OFF);
    float* partials = (float*)(ws + WS_PART_OFF);
    // bf16 scratch inside d_out (12 MB < 16.8 MB); overwritten by outputs later
    unsigned short* z16 = (unsigned short*)d_out;
    unsigned short* cb16 = z16 + (size_t)NROWS * DDIM;

    prep_kernel<<<dim3((KCB + NROWS) / 64), 256, 0, stream>>>(z, cb, z16, cb16, esq, zsq);
    gemm_filter_kernel<<<dim3(16, NROWS / 64), 512, 0, stream>>>(z16, cb16, esq, cand);
    resolve_gather_kernel<<<dim3(NROWS / 4), 256, 0, stream>>>(z, cb, zsq, esq, cand, out, partials);
    final_kernel<<<1, 256, 0, stream>>>(partials, out);
}

// Round 14
// 199.420 us; speedup vs baseline: 1.6738x; 1.0399x over previous
//
#include <hip/hip_runtime.h>
#include <hip/hip_bf16.h>
#include <float.h>

// Problem constants (B,H,W,D,K) = (16,32,32,256,8192)
#define NROWS 16384
#define DDIM  256
#define KCB   8192
#define ZQ_ELEMS 4194304

// ws layout (~2.2 MB; r0-proven)
#define WS_ESQ_OFF   0                      // float[8192]
#define WS_ZSQ_OFF   32768                  // float[16384]
#define WS_CAND_OFF  98304                  // u32[16384*32] = 2 MB
#define WS_PART_OFF  (98304 + 2097152)      // float[4096]

#define QWINDOW 410   // rescore window: 0.025 in 1/16384 fixed-point quanta

typedef __attribute__((ext_vector_type(8))) short short8;
typedef __attribute__((ext_vector_type(4))) float floatx4;

__device__ __forceinline__ unsigned short bf16_rn(float f) {
    unsigned u = __float_as_uint(f);
    return (unsigned short)((u + 0x7FFFu + ((u >> 16) & 1u)) >> 16);
}

// async global->LDS DMA, 16 B per lane; LDS dest = wave-uniform base + lane*16
__device__ __forceinline__ void gload_lds16(const void* g, void* l) {
    __builtin_amdgcn_global_load_lds(
        (const __attribute__((address_space(1))) void*)(uintptr_t)g,
        (__attribute__((address_space(3))) void*)(unsigned)(uintptr_t)l, 16, 0, 0);
}

// ---------- prep: bf16 convert + numpy-pairwise sumsq (bit-exact, proven r3) ----
__global__ __launch_bounds__(256) void prep_kernel(
    const float* __restrict__ z, const float* __restrict__ cb,
    unsigned short* __restrict__ z16, unsigned short* __restrict__ cb16,
    float* __restrict__ esq, float* __restrict__ zsq) {
#pragma clang fp contract(off)
    int tid = threadIdx.x;
    int rowb = tid >> 2, sub = tid & 3;
    int b = sub >> 1, jq = sub & 1;
    int row = blockIdx.x * 64 + rowb;
    const float* src; unsigned short* dst; float* o;
    if (row < KCB) { src = cb + (size_t)row * DDIM; dst = cb16 + (size_t)row * DDIM; o = esq + row; }
    else { int r = row - KCB; src = z + (size_t)r * DDIM; dst = z16 + (size_t)r * DDIM; o = zsq + r; }
    float r0 = 0.f, r1 = 0.f, r2 = 0.f, r3 = 0.f;
#pragma unroll
    for (int t = 0; t < 16; ++t) {
        int off = b * 128 + t * 8 + jq * 4;
        float4 v = *(const float4*)(src + off);
        float q0 = v.x * v.x, q1 = v.y * v.y, q2 = v.z * v.z, q3 = v.w * v.w;
        r0 = r0 + q0; r1 = r1 + q1; r2 = r2 + q2; r3 = r3 + q3;
        ushort4 w;
        w.x = bf16_rn(v.x); w.y = bf16_rn(v.y); w.z = bf16_rn(v.z); w.w = bf16_rn(v.w);
        *(ushort4*)(dst + off) = w;
    }
    float s = (r0 + r1) + (r2 + r3);
    s = s + __shfl_xor(s, 1);   // jq pair
    s = s + __shfl_xor(s, 2);   // block pair
    if (sub == 0) *o = s;
}

// ---------- bf16 MFMA filter: R6 VERBATIM (best measured: 113.2us, absmax 0) ----
// NOTE: mfma_32x32x16 switch analyzed and rejected — in this geometry the
// per-step ds_read/VALU counts are IDENTICAL (A amortized across ct either
// way); only the MFMA pipe 38.8->32 cyc/step ~ -5us, at high layout-bug risk.
__global__ __launch_bounds__(512, 4) void gemm_filter_kernel(
    const unsigned short* __restrict__ z16, const unsigned short* __restrict__ cb16,
    const float* __restrict__ esq, unsigned* __restrict__ cand) {
    __shared__ unsigned short As[64 * 256];     // 32 KB
    __shared__ unsigned short Bs[2][128 * 64];  // 2 x 16 KB
    __shared__ unsigned st[64][4][2];           // 2 KB cross-wave top-2 merge

    const int tid = threadIdx.x;
    const int w = tid >> 6, lane = tid & 63;
    const int wm = w >> 2, wn = w & 3;          // wave tile: rows wm*32+, cols wn*32 per chunk
    const int c = lane & 15, q = lane >> 4;
    const int m0 = blockIdx.y * 64;
    const int nbase = blockIdx.x * 512;

    // prologue: A tile (4 DMA ops/wave) + B chunk 0 (2 ops/wave)
#pragma unroll
    for (int p = 0; p < 4; ++p) {
        int s = (w * 4 + p) * 64 + lane;
        int row = s >> 5, jp = s & 31;
        int j = (jp & 24) | ((jp & 7) ^ (row & 7));   // source-addr XOR swizzle
        gload_lds16(z16 + (size_t)(m0 + row) * 256 + j * 8,
                    (char*)As + (w * 4 + p) * 1024);
    }
#pragma unroll
    for (int p = 0; p < 2; ++p) {
        int s = (w * 2 + p) * 64 + lane;
        int col = s >> 3, jp = s & 7;
        int j = jp ^ (col & 7);
        gload_lds16(cb16 + (size_t)(nbase + col) * 256 + j * 8,
                    (char*)Bs[0] + (w * 2 + p) * 1024);
    }
    __syncthreads();

    floatx4 acc[4][2][2];   // [ct][f][nf] — 64 regs
#pragma unroll
    for (int ct = 0; ct < 4; ++ct)
#pragma unroll
        for (int f = 0; f < 2; ++f)
#pragma unroll
            for (int nf = 0; nf < 2; ++nf) acc[ct][f][nf] = (floatx4){0.f, 0.f, 0.f, 0.f};

    short8 af[2][2];   // [f][ks] for current kt

#pragma unroll
    for (int s5 = 0; s5 < 16; ++s5) {
        const int kt = s5 >> 2, ct = s5 & 3, cur = s5 & 1;
        if (s5 < 15) {   // prefetch next cb chunk into other buffer
            const int nkt = (s5 + 1) >> 2, nct = (s5 + 1) & 3;
#pragma unroll
            for (int p = 0; p < 2; ++p) {
                int s = (w * 2 + p) * 64 + lane;
                int col = s >> 3, jp = s & 7;
                int j = jp ^ (col & 7);
                gload_lds16(cb16 + (size_t)(nbase + nct * 128 + col) * 256 + nkt * 64 + j * 8,
                            (char*)Bs[cur ^ 1] + (w * 2 + p) * 1024);
            }
        }
        if (ct == 0) {   // A-frags for this kt (reused across 4 ct)
#pragma unroll
            for (int f = 0; f < 2; ++f)
#pragma unroll
                for (int ks = 0; ks < 2; ++ks) {
                    int row = wm * 32 + f * 16 + c;
                    af[f][ks] = *(const short8*)((const char*)As + row * 512 +
                                 (kt * 8 + (((ks * 4 + q)) ^ (row & 7))) * 16);
                }
        }
        short8 bf[2][2];
#pragma unroll
        for (int nf = 0; nf < 2; ++nf)
#pragma unroll
            for (int ks = 0; ks < 2; ++ks) {
                int col = wn * 32 + nf * 16 + c;
                bf[nf][ks] = *(const short8*)((const char*)Bs[cur] + col * 128 +
                              (((ks * 4 + q) ^ (col & 7))) * 16);
            }
#pragma unroll
        for (int f = 0; f < 2; ++f)
#pragma unroll
            for (int nf = 0; nf < 2; ++nf) {
                acc[ct][f][nf] = __builtin_amdgcn_mfma_f32_16x16x32_bf16(
                    af[f][0], bf[nf][0], acc[ct][f][nf], 0, 0, 0);
                acc[ct][f][nf] = __builtin_amdgcn_mfma_f32_16x16x32_bf16(
                    af[f][1], bf[nf][1], acc[ct][f][nf], 0, 0, 0);
            }
        __syncthreads();   // buf cur consumed; next chunk's DMA drained here
    }

    // ---- epilogue (once per block): fixed-point pack + top-2 ----
    float ekf[4][2]; unsigned kb[4][2];
#pragma unroll
    for (int ct = 0; ct < 4; ++ct)
#pragma unroll
        for (int nf = 0; nf < 2; ++nf) {
            int col = nbase + ct * 128 + wn * 32 + nf * 16 + c;
            ekf[ct][nf] = (esq[col] + 8.0f) * 16384.0f;   // key+8 in quanta
            kb[ct][nf] = (unsigned)col;
        }
    unsigned b1[2][4], b2[2][4];
#pragma unroll
    for (int f = 0; f < 2; ++f)
#pragma unroll
        for (int r = 0; r < 4; ++r) { b1[f][r] = 0xFFFFFFFFu; b2[f][r] = 0xFFFFFFFFu; }
#pragma unroll
    for (int f = 0; f < 2; ++f)
#pragma unroll
        for (int r = 0; r < 4; ++r)
#pragma unroll
            for (int ct = 0; ct < 4; ++ct)
#pragma unroll
                for (int nf = 0; nf < 2; ++nf) {
                    float fx = fmaf(-32768.0f, acc[ct][f][nf][r], ekf[ct][nf]);
                    unsigned p = ((unsigned)fx << 13) | kb[ct][nf];
                    unsigned nb2;   // top-2 insert: b2 = med3(p,b1,b2); b1 = min(b1,p)
                    asm("v_med3_u32 %0, %1, %2, %3"
                        : "=v"(nb2) : "v"(p), "v"(b1[f][r]), "v"(b2[f][r]));
                    b2[f][r] = nb2;
                    b1[f][r] = min(b1[f][r], p);
                }
#pragma unroll
    for (int f = 0; f < 2; ++f)
#pragma unroll
        for (int r = 0; r < 4; ++r) {
            unsigned x1 = b1[f][r], x2 = b2[f][r];
#pragma unroll
            for (int sft = 1; sft < 16; sft <<= 1) {
                unsigned o1 = __shfl_xor(x1, sft);
                unsigned o2 = __shfl_xor(x2, sft);
                unsigned mx = max(x1, o1);
                x1 = min(x1, o1);
                x2 = min(min(mx, x2), o2);
            }
            if (c == 0) {
                st[wm * 32 + f * 16 + q * 4 + r][wn][0] = x1;
                st[wm * 32 + f * 16 + q * 4 + r][wn][1] = x2;
            }
        }
    __syncthreads();
    if (tid < 64) {
        unsigned a1 = st[tid][0][0], a2 = st[tid][0][1];
#pragma unroll
        for (int ww = 1; ww < 4; ++ww) {
            unsigned p1 = st[tid][ww][0], p2 = st[tid][ww][1];
            unsigned mx = max(a1, p1);
            a1 = min(a1, p1);
            a2 = min(min(mx, a2), p2);
        }
        cand[(size_t)(m0 + tid) * 32 + blockIdx.x * 2 + 0] = a1;
        cand[(size_t)(m0 + tid) * 32 + blockIdx.x * 2 + 1] = a2;
    }
}

// ---------- resolve: coalesced-gather rescore, v2 ------------------------------
// R13 (-30us) proved the uncoalesced-gather theory. v2 attacks the residual
// ~93% stall: (1) LDS 37->20.7KB (slots 8->4, pad 260): 4->7 blocks/CU for
// latency hiding of the serial phases; (2) chain reads vectorized to float4
// (512 ds_read_b32 -> 128 ds_read_b128; fmaf order x,y,z,w = d..d+3 UNCHANGED);
// (3) winner gather reads z/e from their staged LDS bit-copies (slot carried
// through the reduction) instead of 8 more global loads. All data paths are
// bit-copies and all fp chains order-identical -> absmax 0 by construction.
// Window population: dist spread sigma ~0.6 >> window 0.025 -> active count
// typically 1-3; rank>=4 overflow falls back to the identical-order global chain.
__global__ __launch_bounds__(256) void resolve_gather_kernel(
    const float* __restrict__ z, const float* __restrict__ cb,
    const float* __restrict__ zsq, const float* __restrict__ esq,
    const unsigned* __restrict__ cand, float* __restrict__ out,
    float* __restrict__ partials) {
#pragma clang fp contract(off)
    __shared__ float ers[4][4][260];   // 16.6 KB staged candidate rows (260%4==0: float4-aligned; slot stride -> distinct bank-quads)
    __shared__ float zs[4][256];       // 4 KB: the wave's z row (bit-copy)
    __shared__ float wls[4];
    int wv = threadIdx.x >> 6, l = threadIdx.x & 63;
    int row = blockIdx.x * 4 + wv;
    unsigned p = (l < 32) ? cand[(size_t)row * 32 + l] : 0xFFFFFFFFu;
    unsigned m = p;
#pragma unroll
    for (int s = 32; s; s >>= 1) m = min(m, __shfl_xor(m, s));
    bool active = (l < 32) && ((p >> 13) <= (m >> 13) + QWINDOW);
    int k = active ? (int)(p & 8191u) : 0x7FFFFFFF;

    // rank among active lanes; ranks 0..3 get LDS slots (in lane order)
    unsigned long long bal = __ballot(active);
    int rank = __popcll(bal & ((1ull << l) - 1ull));
    int nst = __popcll(bal); nst = nst < 4 ? nst : 4;

    // stage z row (coalesced, once per wave; bit-copy)
    *(float4*)&zs[wv][l * 4] = *(const float4*)(z + (size_t)row * DDIM + l * 4);
    // stage up to 4 candidate rows, one coalesced 1KB load each (bit-copies)
    unsigned long long tmp = bal;
    for (int s = 0; s < nst; ++s) {
        int src = (int)__builtin_ctzll(tmp);
        tmp &= tmp - 1ull;
        int kk = __shfl(k, src, 64);
        *(float4*)&ers[wv][s][l * 4] = *(const float4*)(cb + (size_t)kk * DDIM + l * 4);
    }

    int sl = (active && rank < 4) ? rank : 99;
    float dref = FLT_MAX;
    if (active) {
        float cacc = 0.f;
        if (sl < 4) {   // LDS path: float4 reads, fmaf order d,d+1,d+2,d+3 (identical)
            const float* zrow = &zs[wv][0];
            const float* erow = &ers[wv][sl][0];
#pragma unroll 4
            for (int d = 0; d < DDIM; d += 4) {
                float4 zv = *(const float4*)(zrow + d);
                float4 ev = *(const float4*)(erow + d);
                cacc = fmaf(zv.x, ev.x, cacc);
                cacc = fmaf(zv.y, ev.y, cacc);
                cacc = fmaf(zv.z, ev.z, cacc);
                cacc = fmaf(zv.w, ev.w, cacc);
            }
        } else {        // overflow fallback: global chain, same fp order
            const float* zr = z + (size_t)row * DDIM;
            const float* er = cb + (size_t)k * DDIM;
#pragma unroll 4
            for (int d = 0; d < DDIM; d += 4) {
                float4 zv = *(const float4*)(zr + d);
                float4 ev = *(const float4*)(er + d);
                cacc = fmaf(zv.x, ev.x, cacc);
                cacc = fmaf(zv.y, ev.y, cacc);
                cacc = fmaf(zv.z, ev.z, cacc);
                cacc = fmaf(zv.w, ev.w, cacc);
            }
        }
        float s1 = zsq[row] + esq[k];          // numpy: z_sq + e_sq (fp32 round)
        float two = 2.0f * cacc;               // exact
        dref = s1 - two;                       // single fp32 round
    }
    // winner reduce, carrying the slot of the winning lane
#pragma unroll
    for (int s = 32; s; s >>= 1) {
        float od = __shfl_xor(dref, s);
        int ok = __shfl_xor(k, s);
        int osl = __shfl_xor(sl, s);
        if (od < dref || (od == dref && ok < k)) { dref = od; k = ok; sl = osl; }
    }
    if (l == 0) out[ZQ_ELEMS + row] = (float)k;
    float ls = 0.f;
    bool lds_ok = (sl < 4);   // winner row staged? (wave-uniform after reduce)
#pragma unroll
    for (int t = 0; t < 4; ++t) {
        int d = l + t * 64;
        float e = lds_ok ? ers[wv][sl][d] : cb[(size_t)k * DDIM + d];   // bit-copy either way
        float zv = zs[wv][d];                                           // bit-copy of z
        out[(size_t)row * DDIM + d] = zv + (e - zv);  // z_q_st == z_q numerically
        float df = zv - e;
        ls = fmaf(df, df, ls);
    }
#pragma unroll
    for (int s = 32; s; s >>= 1) ls += __shfl_xor(ls, s);
    if (l == 0) wls[wv] = ls;
    __syncthreads();
    if (threadIdx.x == 0)
        partials[blockIdx.x] = (wls[0] + wls[1]) + (wls[2] + wls[3]);
}

__global__ __launch_bounds__(256) void final_kernel(const float* __restrict__ partials,
                                                    float* __restrict__ out) {
    __shared__ double wd[4];
    int w = threadIdx.x >> 6, l = threadIdx.x & 63;
    double s = 0.0;
#pragma unroll
    for (int j = 0; j < 16; ++j) s += (double)partials[threadIdx.x + j * 256];
#pragma unroll
    for (int sh = 32; sh; sh >>= 1) s += __shfl_xor(s, sh);
    if (l == 0) wd[w] = s;
    __syncthreads();
    if (threadIdx.x == 0)
        out[ZQ_ELEMS + NROWS] =
            (float)(1.25 * ((wd[0] + wd[1]) + (wd[2] + wd[3])) / (double)ZQ_ELEMS);
}

extern "C" void kernel_launch(void* const* d_in, const int* in_sizes, int n_in,
                              void* d_out, int out_size, void* d_ws, size_t ws_size,
                              hipStream_t stream) {
    const float* z = (const float*)d_in[0];
    const float* cb = (const float*)d_in[1];
    float* out = (float*)d_out;
    char* ws = (char*)d_ws;
    float* esq = (float*)(ws + WS_ESQ_OFF);
    float* zsq = (float*)(ws + WS_ZSQ_OFF);
    unsigned* cand = (unsigned*)(ws + WS_CAND_OFF);
    float* partials = (float*)(ws + WS_PART_OFF);
    // bf16 scratch inside d_out (12 MB < 16.8 MB); overwritten by outputs later
    unsigned short* z16 = (unsigned short*)d_out;
    unsigned short* cb16 = z16 + (size_t)NROWS * DDIM;

    prep_kernel<<<dim3((KCB + NROWS) / 64), 256, 0, stream>>>(z, cb, z16, cb16, esq, zsq);
    gemm_filter_kernel<<<dim3(16, NROWS / 64), 512, 0, stream>>>(z16, cb16, esq, cand);
    resolve_gather_kernel<<<dim3(NROWS / 4), 256, 0, stream>>>(z, cb, zsq, esq, cand, out, partials);
    final_kernel<<<1, 256, 0, stream>>>(partials, out);
}

// Round 15
// 188.656 us; speedup vs baseline: 1.7693x; 1.0571x over previous
//
#include <hip/hip_runtime.h>
#include <hip/hip_bf16.h>
#include <float.h>

// Problem constants (B,H,W,D,K) = (16,32,32,256,8192)
#define NROWS 16384
#define DDIM  256
#define KCB   8192
#define ZQ_ELEMS 4194304

// ws layout (~2.2 MB; r0-proven)
#define WS_ESQ_OFF   0                      // float[8192]
#define WS_ZSQ_OFF   32768                  // float[16384]
#define WS_CAND_OFF  98304                  // u32[16384*32] = 2 MB
#define WS_PART_OFF  (98304 + 2097152)      // float[4096]

#define QWINDOW 410   // rescore window: 0.025 in 1/16384 fixed-point quanta

typedef __attribute__((ext_vector_type(8))) short short8;
typedef __attribute__((ext_vector_type(4))) float floatx4;

__device__ __forceinline__ unsigned short bf16_rn(float f) {
    unsigned u = __float_as_uint(f);
    return (unsigned short)((u + 0x7FFFu + ((u >> 16) & 1u)) >> 16);
}

// async global->LDS DMA, 16 B per lane; LDS dest = wave-uniform base + lane*16
__device__ __forceinline__ void gload_lds16(const void* g, void* l) {
    __builtin_amdgcn_global_load_lds(
        (const __attribute__((address_space(1))) void*)(uintptr_t)g,
        (__attribute__((address_space(3))) void*)(unsigned)(uintptr_t)l, 16, 0, 0);
}

// ---------- prep: bf16 convert + numpy-pairwise sumsq (bit-exact, proven r3) ----
__global__ __launch_bounds__(256) void prep_kernel(
    const float* __restrict__ z, const float* __restrict__ cb,
    unsigned short* __restrict__ z16, unsigned short* __restrict__ cb16,
    float* __restrict__ esq, float* __restrict__ zsq) {
#pragma clang fp contract(off)
    int tid = threadIdx.x;
    int rowb = tid >> 2, sub = tid & 3;
    int b = sub >> 1, jq = sub & 1;
    int row = blockIdx.x * 64 + rowb;
    const float* src; unsigned short* dst; float* o;
    if (row < KCB) { src = cb + (size_t)row * DDIM; dst = cb16 + (size_t)row * DDIM; o = esq + row; }
    else { int r = row - KCB; src = z + (size_t)r * DDIM; dst = z16 + (size_t)r * DDIM; o = zsq + r; }
    float r0 = 0.f, r1 = 0.f, r2 = 0.f, r3 = 0.f;
#pragma unroll
    for (int t = 0; t < 16; ++t) {
        int off = b * 128 + t * 8 + jq * 4;
        float4 v = *(const float4*)(src + off);
        float q0 = v.x * v.x, q1 = v.y * v.y, q2 = v.z * v.z, q3 = v.w * v.w;
        r0 = r0 + q0; r1 = r1 + q1; r2 = r2 + q2; r3 = r3 + q3;
        ushort4 w;
        w.x = bf16_rn(v.x); w.y = bf16_rn(v.y); w.z = bf16_rn(v.z); w.w = bf16_rn(v.w);
        *(ushort4*)(dst + off) = w;
    }
    float s = (r0 + r1) + (r2 + r3);
    s = s + __shfl_xor(s, 1);   // jq pair
    s = s + __shfl_xor(s, 2);   // block pair
    if (sub == 0) *o = s;
}

// ---------- bf16 MFMA filter: R6 VERBATIM (best measured: 113.2us, absmax 0) ----
__global__ __launch_bounds__(512, 4) void gemm_filter_kernel(
    const unsigned short* __restrict__ z16, const unsigned short* __restrict__ cb16,
    const float* __restrict__ esq, unsigned* __restrict__ cand) {
    __shared__ unsigned short As[64 * 256];     // 32 KB
    __shared__ unsigned short Bs[2][128 * 64];  // 2 x 16 KB
    __shared__ unsigned st[64][4][2];           // 2 KB cross-wave top-2 merge

    const int tid = threadIdx.x;
    const int w = tid >> 6, lane = tid & 63;
    const int wm = w >> 2, wn = w & 3;          // wave tile: rows wm*32+, cols wn*32 per chunk
    const int c = lane & 15, q = lane >> 4;
    const int m0 = blockIdx.y * 64;
    const int nbase = blockIdx.x * 512;

    // prologue: A tile (4 DMA ops/wave) + B chunk 0 (2 ops/wave)
#pragma unroll
    for (int p = 0; p < 4; ++p) {
        int s = (w * 4 + p) * 64 + lane;
        int row = s >> 5, jp = s & 31;
        int j = (jp & 24) | ((jp & 7) ^ (row & 7));   // source-addr XOR swizzle
        gload_lds16(z16 + (size_t)(m0 + row) * 256 + j * 8,
                    (char*)As + (w * 4 + p) * 1024);
    }
#pragma unroll
    for (int p = 0; p < 2; ++p) {
        int s = (w * 2 + p) * 64 + lane;
        int col = s >> 3, jp = s & 7;
        int j = jp ^ (col & 7);
        gload_lds16(cb16 + (size_t)(nbase + col) * 256 + j * 8,
                    (char*)Bs[0] + (w * 2 + p) * 1024);
    }
    __syncthreads();

    floatx4 acc[4][2][2];   // [ct][f][nf] — 64 regs
#pragma unroll
    for (int ct = 0; ct < 4; ++ct)
#pragma unroll
        for (int f = 0; f < 2; ++f)
#pragma unroll
            for (int nf = 0; nf < 2; ++nf) acc[ct][f][nf] = (floatx4){0.f, 0.f, 0.f, 0.f};

    short8 af[2][2];   // [f][ks] for current kt

#pragma unroll
    for (int s5 = 0; s5 < 16; ++s5) {
        const int kt = s5 >> 2, ct = s5 & 3, cur = s5 & 1;
        if (s5 < 15) {   // prefetch next cb chunk into other buffer
            const int nkt = (s5 + 1) >> 2, nct = (s5 + 1) & 3;
#pragma unroll
            for (int p = 0; p < 2; ++p) {
                int s = (w * 2 + p) * 64 + lane;
                int col = s >> 3, jp = s & 7;
                int j = jp ^ (col & 7);
                gload_lds16(cb16 + (size_t)(nbase + nct * 128 + col) * 256 + nkt * 64 + j * 8,
                            (char*)Bs[cur ^ 1] + (w * 2 + p) * 1024);
            }
        }
        if (ct == 0) {   // A-frags for this kt (reused across 4 ct)
#pragma unroll
            for (int f = 0; f < 2; ++f)
#pragma unroll
                for (int ks = 0; ks < 2; ++ks) {
                    int row = wm * 32 + f * 16 + c;
                    af[f][ks] = *(const short8*)((const char*)As + row * 512 +
                                 (kt * 8 + (((ks * 4 + q)) ^ (row & 7))) * 16);
                }
        }
        short8 bf[2][2];
#pragma unroll
        for (int nf = 0; nf < 2; ++nf)
#pragma unroll
            for (int ks = 0; ks < 2; ++ks) {
                int col = wn * 32 + nf * 16 + c;
                bf[nf][ks] = *(const short8*)((const char*)Bs[cur] + col * 128 +
                              (((ks * 4 + q) ^ (col & 7))) * 16);
            }
#pragma unroll
        for (int f = 0; f < 2; ++f)
#pragma unroll
            for (int nf = 0; nf < 2; ++nf) {
                acc[ct][f][nf] = __builtin_amdgcn_mfma_f32_16x16x32_bf16(
                    af[f][0], bf[nf][0], acc[ct][f][nf], 0, 0, 0);
                acc[ct][f][nf] = __builtin_amdgcn_mfma_f32_16x16x32_bf16(
                    af[f][1], bf[nf][1], acc[ct][f][nf], 0, 0, 0);
            }
        __syncthreads();   // buf cur consumed; next chunk's DMA drained here
    }

    // ---- epilogue (once per block): fixed-point pack + top-2 ----
    float ekf[4][2]; unsigned kb[4][2];
#pragma unroll
    for (int ct = 0; ct < 4; ++ct)
#pragma unroll
        for (int nf = 0; nf < 2; ++nf) {
            int col = nbase + ct * 128 + wn * 32 + nf * 16 + c;
            ekf[ct][nf] = (esq[col] + 8.0f) * 16384.0f;   // key+8 in quanta
            kb[ct][nf] = (unsigned)col;
        }
    unsigned b1[2][4], b2[2][4];
#pragma unroll
    for (int f = 0; f < 2; ++f)
#pragma unroll
        for (int r = 0; r < 4; ++r) { b1[f][r] = 0xFFFFFFFFu; b2[f][r] = 0xFFFFFFFFu; }
#pragma unroll
    for (int f = 0; f < 2; ++f)
#pragma unroll
        for (int r = 0; r < 4; ++r)
#pragma unroll
            for (int ct = 0; ct < 4; ++ct)
#pragma unroll
                for (int nf = 0; nf < 2; ++nf) {
                    float fx = fmaf(-32768.0f, acc[ct][f][nf][r], ekf[ct][nf]);
                    unsigned p = ((unsigned)fx << 13) | kb[ct][nf];
                    unsigned nb2;   // top-2 insert: b2 = med3(p,b1,b2); b1 = min(b1,p)
                    asm("v_med3_u32 %0, %1, %2, %3"
                        : "=v"(nb2) : "v"(p), "v"(b1[f][r]), "v"(b2[f][r]));
                    b2[f][r] = nb2;
                    b1[f][r] = min(b1[f][r], p);
                }
#pragma unroll
    for (int f = 0; f < 2; ++f)
#pragma unroll
        for (int r = 0; r < 4; ++r) {
            unsigned x1 = b1[f][r], x2 = b2[f][r];
#pragma unroll
            for (int sft = 1; sft < 16; sft <<= 1) {
                unsigned o1 = __shfl_xor(x1, sft);
                unsigned o2 = __shfl_xor(x2, sft);
                unsigned mx = max(x1, o1);
                x1 = min(x1, o1);
                x2 = min(min(mx, x2), o2);
            }
            if (c == 0) {
                st[wm * 32 + f * 16 + q * 4 + r][wn][0] = x1;
                st[wm * 32 + f * 16 + q * 4 + r][wn][1] = x2;
            }
        }
    __syncthreads();
    if (tid < 64) {
        unsigned a1 = st[tid][0][0], a2 = st[tid][0][1];
#pragma unroll
        for (int ww = 1; ww < 4; ++ww) {
            unsigned p1 = st[tid][ww][0], p2 = st[tid][ww][1];
            unsigned mx = max(a1, p1);
            a1 = min(a1, p1);
            a2 = min(min(mx, a2), p2);
        }
        cand[(size_t)(m0 + tid) * 32 + blockIdx.x * 2 + 0] = a1;
        cand[(size_t)(m0 + tid) * 32 + blockIdx.x * 2 + 1] = a2;
    }
}

// ---------- resolve: coalesced-gather rescore, v3 ------------------------------
// v2 (R14, -8us) proven. v3 adds the SINGLE-CANDIDATE FAST PATH: when exactly
// one candidate is inside the window (statistics: best-to-2nd gap ~ sigma/
// (n*phi) ~ 0.19 >> window 0.025 -> ~85% of rows), the winner is that
// candidate REGARDLESS of its fp32 score (the lexicographic (dref,k) reduce
// over one active lane returns it for any dref) -> skip ers staging and the
// entire fmaf chain. Bit-exact by construction: k identical, dref is not an
// output, gather (global-cb path, as the rank>=4 overflow already uses) and
// the ls chain are unchanged. nact>=2 takes v2's proven path untouched.
__global__ __launch_bounds__(256) void resolve_gather_kernel(
    const float* __restrict__ z, const float* __restrict__ cb,
    const float* __restrict__ zsq, const float* __restrict__ esq,
    const unsigned* __restrict__ cand, float* __restrict__ out,
    float* __restrict__ partials) {
#pragma clang fp contract(off)
    __shared__ float ers[4][4][260];   // 16.6 KB staged candidate rows
    __shared__ float zs[4][256];       // 4 KB: the wave's z row (bit-copy)
    __shared__ float wls[4];
    int wv = threadIdx.x >> 6, l = threadIdx.x & 63;
    int row = blockIdx.x * 4 + wv;
    unsigned p = (l < 32) ? cand[(size_t)row * 32 + l] : 0xFFFFFFFFu;
    unsigned m = p;
#pragma unroll
    for (int s = 32; s; s >>= 1) m = min(m, __shfl_xor(m, s));
    bool active = (l < 32) && ((p >> 13) <= (m >> 13) + QWINDOW);
    int k = active ? (int)(p & 8191u) : 0x7FFFFFFF;

    unsigned long long bal = __ballot(active);
    int nact = __popcll(bal);

    // stage z row (coalesced, once per wave; bit-copy) — feeds gather & ls
    *(float4*)&zs[wv][l * 4] = *(const float4*)(z + (size_t)row * DDIM + l * 4);

    float dref = FLT_MAX;
    int sl = 99;
    if (nact == 1) {
        // sole in-window candidate wins without rescoring (k unchanged;
        // dref only participates in the compare). No staging, no chain.
        if (active) dref = 0.0f;
    } else {
        // rank among active lanes; ranks 0..3 get LDS slots (in lane order)
        int rank = __popcll(bal & ((1ull << l) - 1ull));
        int nst = nact < 4 ? nact : 4;
        unsigned long long tmp = bal;
        for (int s = 0; s < nst; ++s) {
            int src = (int)__builtin_ctzll(tmp);
            tmp &= tmp - 1ull;
            int kk = __shfl(k, src, 64);
            *(float4*)&ers[wv][s][l * 4] = *(const float4*)(cb + (size_t)kk * DDIM + l * 4);
        }
        sl = (active && rank < 4) ? rank : 99;
        if (active) {
            float cacc = 0.f;
            if (sl < 4) {   // LDS path: float4 reads, fmaf order d..d+3 (identical)
                const float* zrow = &zs[wv][0];
                const float* erow = &ers[wv][sl][0];
#pragma unroll 4
                for (int d = 0; d < DDIM; d += 4) {
                    float4 zv = *(const float4*)(zrow + d);
                    float4 ev = *(const float4*)(erow + d);
                    cacc = fmaf(zv.x, ev.x, cacc);
                    cacc = fmaf(zv.y, ev.y, cacc);
                    cacc = fmaf(zv.z, ev.z, cacc);
                    cacc = fmaf(zv.w, ev.w, cacc);
                }
            } else {        // overflow fallback: global chain, same fp order
                const float* zr = z + (size_t)row * DDIM;
                const float* er = cb + (size_t)k * DDIM;
#pragma unroll 4
                for (int d = 0; d < DDIM; d += 4) {
                    float4 zv = *(const float4*)(zr + d);
                    float4 ev = *(const float4*)(er + d);
                    cacc = fmaf(zv.x, ev.x, cacc);
                    cacc = fmaf(zv.y, ev.y, cacc);
                    cacc = fmaf(zv.z, ev.z, cacc);
                    cacc = fmaf(zv.w, ev.w, cacc);
                }
            }
            float s1 = zsq[row] + esq[k];          // numpy: z_sq + e_sq (fp32 round)
            float two = 2.0f * cacc;               // exact
            dref = s1 - two;                       // single fp32 round
        }
    }
    // winner reduce, carrying the slot of the winning lane
#pragma unroll
    for (int s = 32; s; s >>= 1) {
        float od = __shfl_xor(dref, s);
        int ok = __shfl_xor(k, s);
        int osl = __shfl_xor(sl, s);
        if (od < dref || (od == dref && ok < k)) { dref = od; k = ok; sl = osl; }
    }
    if (l == 0) out[ZQ_ELEMS + row] = (float)k;
    float ls = 0.f;
    bool lds_ok = (sl < 4);   // winner row staged? (wave-uniform after reduce)
#pragma unroll
    for (int t = 0; t < 4; ++t) {
        int d = l + t * 64;
        float e = lds_ok ? ers[wv][sl][d] : cb[(size_t)k * DDIM + d];   // bit-copy either way
        float zv = zs[wv][d];                                           // bit-copy of z
        out[(size_t)row * DDIM + d] = zv + (e - zv);  // z_q_st == z_q numerically
        float df = zv - e;
        ls = fmaf(df, df, ls);
    }
#pragma unroll
    for (int s = 32; s; s >>= 1) ls += __shfl_xor(ls, s);
    if (l == 0) wls[wv] = ls;
    __syncthreads();
    if (threadIdx.x == 0)
        partials[blockIdx.x] = (wls[0] + wls[1]) + (wls[2] + wls[3]);
}

__global__ __launch_bounds__(256) void final_kernel(const float* __restrict__ partials,
                                                    float* __restrict__ out) {
    __shared__ double wd[4];
    int w = threadIdx.x >> 6, l = threadIdx.x & 63;
    double s = 0.0;
#pragma unroll
    for (int j = 0; j < 16; ++j) s += (double)partials[threadIdx.x + j * 256];
#pragma unroll
    for (int sh = 32; sh; sh >>= 1) s += __shfl_xor(s, sh);
    if (l == 0) wd[w] = s;
    __syncthreads();
    if (threadIdx.x == 0)
        out[ZQ_ELEMS + NROWS] =
            (float)(1.25 * ((wd[0] + wd[1]) + (wd[2] + wd[3])) / (double)ZQ_ELEMS);
}

extern "C" void kernel_launch(void* const* d_in, const int* in_sizes, int n_in,
                              void* d_out, int out_size, void* d_ws, size_t ws_size,
                              hipStream_t stream) {
    const float* z = (const float*)d_in[0];
    const float* cb = (const float*)d_in[1];
    float* out = (float*)d_out;
    char* ws = (char*)d_ws;
    float* esq = (float*)(ws + WS_ESQ_OFF);
    float* zsq = (float*)(ws + WS_ZSQ_OFF);
    unsigned* cand = (unsigned*)(ws + WS_CAND_OFF);
    float* partials = (float*)(ws + WS_PART_OFF);
    // bf16 scratch inside d_out (12 MB < 16.8 MB); overwritten by outputs later
    unsigned short* z16 = (unsigned short*)d_out;
    unsigned short* cb16 = z16 + (size_t)NROWS * DDIM;

    prep_kernel<<<dim3((KCB + NROWS) / 64), 256, 0, stream>>>(z, cb, z16, cb16, esq, zsq);
    gemm_filter_kernel<<<dim3(16, NROWS / 64), 512, 0, stream>>>(z16, cb16, esq, cand);
    resolve_gather_kernel<<<dim3(NROWS / 4), 256, 0, stream>>>(z, cb, zsq, esq, cand, out, partials);
    final_kernel<<<1, 256, 0, stream>>>(partials, out);
}